// Round 5
// baseline (2425.718 us; speedup 1.0000x reference)
//
#include <hip/hip_runtime.h>
#include <math.h>

// Problem constants (match reference)
constexpr int N_  = 50000;
constexpr int E_  = 1600000;
constexpr int F   = 64;
constexpr int DEA = 16;
constexpr int LL  = 3;
constexpr int GG  = 64;
constexpr int HH  = 256;
constexpr int OO  = 2;
constexpr int ZIN = 2 * F + DEA;  // 144
#define EPS_ 1e-5f

// ---------- helpers ----------
__device__ __forceinline__ unsigned int fmap(float f) {
  unsigned int u = __float_as_uint(f);
  return (u & 0x80000000u) ? ~u : (u | 0x80000000u);
}
__device__ __forceinline__ float funmap(unsigned int m) {
  return (m & 0x80000000u) ? __uint_as_float(m ^ 0x80000000u)
                           : __uint_as_float(~m);
}

// ---------- per-node linear projections ----------
// Darr[n][k] = (x[n] @ Wf[0:64])[k] + bf[k]   (.x)  and Ws-version (.y)
// Sarr[n][k] = (x[n] @ Wf[64:128])[k]         (.x)  and Ws-version (.y)
__global__ __launch_bounds__(256) void node_linear_k(
    const float* __restrict__ x, const float* __restrict__ Wf,
    const float* __restrict__ bf, const float* __restrict__ Ws,
    const float* __restrict__ bs, float2* __restrict__ Darr,
    float2* __restrict__ Sarr) {
  __shared__ float xs[4][64];
  const int wave = threadIdx.x >> 6, lane = threadIdx.x & 63;
  const int n = blockIdx.x * 4 + wave;  // grid = N/4 exact
  xs[wave][lane] = x[n * 64 + lane];
  __syncthreads();
  float df = 0.f, ds = 0.f, sf = 0.f, ss = 0.f;
#pragma unroll 8
  for (int d = 0; d < 64; ++d) {
    const float xv = xs[wave][d];
    df += xv * Wf[d * 64 + lane];
    sf += xv * Wf[(64 + d) * 64 + lane];
    ds += xv * Ws[d * 64 + lane];
    ss += xv * Ws[(64 + d) * 64 + lane];
  }
  Darr[n * 64 + lane] = make_float2(df + bf[lane], ds + bs[lane]);
  Sarr[n * 64 + lane] = make_float2(sf, ss);
}

// ---------- per-edge message + atomic scatter ----------
__global__ __launch_bounds__(256) void edge_msg_k(
    const int* __restrict__ src, const int* __restrict__ dst,
    const float* __restrict__ ea, const float* __restrict__ WfE,
    const float* __restrict__ WsE, const float2* __restrict__ Darr,
    const float2* __restrict__ Sarr, float* __restrict__ agg) {
  __shared__ float wfe_s[DEA * 64];
  __shared__ float wse_s[DEA * 64];
  __shared__ float eash[4][DEA];
  for (int i = threadIdx.x; i < DEA * 64; i += 256) {
    wfe_s[i] = WfE[i];
    wse_s[i] = WsE[i];
  }
  const int wave = threadIdx.x >> 6, lane = threadIdx.x & 63;
  const int e = blockIdx.x * 4 + wave;  // grid = E/4 exact
  const int s = src[e], d0 = dst[e];
  if (lane < DEA) eash[wave][lane] = ea[e * DEA + lane];
  __syncthreads();
  const float2 dv = Darr[d0 * 64 + lane];
  const float2 sv = Sarr[s * 64 + lane];
  float gf = dv.x + sv.x;
  float gs = dv.y + sv.y;
#pragma unroll
  for (int d = 0; d < DEA; ++d) {
    const float av = eash[wave][d];
    gf += av * wfe_s[d * 64 + lane];
    gs += av * wse_s[d * 64 + lane];
  }
  const float sig = 1.f / (1.f + __expf(-gf));
  const float sp = (gs > 20.f) ? gs : log1pf(__expf(gs));
  atomicAdd(&agg[d0 * 64 + lane], sig * sp);
}

// ---------- BN (inference) + residual ----------
__global__ __launch_bounds__(256) void bn_res_k(
    const float* __restrict__ xin, const float* __restrict__ agg,
    const float* __restrict__ g, const float* __restrict__ b,
    const float* __restrict__ m, const float* __restrict__ v,
    float* __restrict__ xout) {
  const int i = blockIdx.x * 256 + threadIdx.x;  // grid = N*F/256 exact
  const int k = i & 63;
  const float sc = rsqrtf(v[k] + EPS_) * g[k];
  xout[i] = xin[i] + (agg[i] - m[k]) * sc + b[k];
}

// ---------- segment max pool (batch sorted) ----------
__global__ __launch_bounds__(256) void pool_max_k(
    const float* __restrict__ x, const int* __restrict__ batch,
    unsigned int* __restrict__ pooled) {
  const int wave_glob = blockIdx.x * 4 + (threadIdx.x >> 6);
  const int lane = threadIdx.x & 63;
  const int n0 = wave_glob * 32;
  if (n0 >= N_) return;
  const int nend = min(n0 + 32, N_);
  int cur_b = batch[n0];
  float mmax = -INFINITY;
  for (int n = n0; n < nend; ++n) {
    const int b = batch[n];
    if (b != cur_b) {
      atomicMax(&pooled[cur_b * 64 + lane], fmap(mmax));
      cur_b = b;
      mmax = -INFINITY;
    }
    mmax = fmaxf(mmax, x[n * 64 + lane]);
  }
  atomicMax(&pooled[cur_b * 64 + lane], fmap(mmax));
}

// ---------- head: h = BN2(relu(pooled @ W1 + b1)) ----------
__global__ __launch_bounds__(256) void head1_k(
    const unsigned int* __restrict__ pooled, const float* __restrict__ W1,
    const float* __restrict__ b1, const float* __restrict__ g2,
    const float* __restrict__ b2n, const float* __restrict__ m2,
    const float* __restrict__ v2, float* __restrict__ h) {
  __shared__ float p[64];
  const int gidx = blockIdx.x;  // grid = GG
  const int j = threadIdx.x;    // 0..255
  if (j < 64) p[j] = funmap(pooled[gidx * 64 + j]);
  __syncthreads();
  float acc = b1[j];
#pragma unroll 8
  for (int k = 0; k < 64; ++k) acc += p[k] * W1[k * HH + j];
  acc = fmaxf(acc, 0.f);
  acc = (acc - m2[j]) * rsqrtf(v2[j] + EPS_) * g2[j] + b2n[j];
  h[gidx * HH + j] = acc;
}

// ---------- head: out = sigmoid(h @ W2 + b2) ----------
__global__ __launch_bounds__(128) void head2_k(
    const float* __restrict__ h, const float* __restrict__ W2,
    const float* __restrict__ b2, float* __restrict__ out) {
  const int t = threadIdx.x;  // 128 threads
  const int gidx = t >> 1, o = t & 1;
  float acc = b2[o];
#pragma unroll 8
  for (int k = 0; k < HH; ++k) acc += h[gidx * HH + k] * W2[k * OO + o];
  out[gidx * OO + o] = 1.f / (1.f + __expf(-acc));
}

extern "C" void kernel_launch(void* const* d_in, const int* in_sizes, int n_in,
                              void* d_out, int out_size, void* d_ws,
                              size_t ws_size, hipStream_t stream) {
  const float* x    = (const float*)d_in[0];
  const int* ei     = (const int*)d_in[1];
  const float* ea   = (const float*)d_in[2];
  const int* batch  = (const int*)d_in[3];
  const float* Wf   = (const float*)d_in[4];
  const float* bf   = (const float*)d_in[5];
  const float* Ws   = (const float*)d_in[6];
  const float* bs   = (const float*)d_in[7];
  const float* bn_g = (const float*)d_in[8];
  const float* bn_b = (const float*)d_in[9];
  const float* bn_m = (const float*)d_in[10];
  const float* bn_v = (const float*)d_in[11];
  const float* W1   = (const float*)d_in[12];
  const float* b1   = (const float*)d_in[13];
  const float* g2   = (const float*)d_in[14];
  const float* b2n  = (const float*)d_in[15];
  const float* m2   = (const float*)d_in[16];
  const float* v2   = (const float*)d_in[17];
  const float* W2   = (const float*)d_in[18];
  const float* b2   = (const float*)d_in[19];
  float* out = (float*)d_out;

  // workspace layout
  char* ws = (char*)d_ws;
  float2* Darr = (float2*)ws;                          // N*64 float2 (25.6 MB)
  float2* Sarr = Darr + (size_t)N_ * 64;               // N*64 float2 (25.6 MB)
  float* x_cur = (float*)(Sarr + (size_t)N_ * 64);     // N*F   (12.8 MB)
  float* agg   = x_cur + (size_t)N_ * F;               // N*F   (12.8 MB)
  unsigned int* pooled = (unsigned int*)(agg + (size_t)N_ * F);  // G*F
  float* h_ws  = (float*)(pooled + GG * F);            // G*H

  const int* srcp = ei;
  const int* dstp = ei + E_;

  for (int l = 0; l < LL; ++l) {
    const float* xin = (l == 0) ? x : x_cur;
    node_linear_k<<<N_ / 4, 256, 0, stream>>>(
        xin, Wf + (size_t)l * ZIN * F, bf + l * F, Ws + (size_t)l * ZIN * F,
        bs + l * F, Darr, Sarr);
    hipMemsetAsync(agg, 0, (size_t)N_ * F * sizeof(float), stream);
    edge_msg_k<<<E_ / 4, 256, 0, stream>>>(
        srcp, dstp, ea, Wf + (size_t)l * ZIN * F + 2 * F * F,
        Ws + (size_t)l * ZIN * F + 2 * F * F, Darr, Sarr, agg);
    bn_res_k<<<(N_ * F) / 256, 256, 0, stream>>>(
        xin, agg, bn_g + l * F, bn_b + l * F, bn_m + l * F, bn_v + l * F,
        x_cur);
  }
  hipMemsetAsync(pooled, 0, GG * F * sizeof(unsigned int), stream);
  const int nwaves = (N_ + 31) / 32;
  pool_max_k<<<(nwaves + 3) / 4, 256, 0, stream>>>(x_cur, batch, pooled);
  head1_k<<<GG, 256, 0, stream>>>(pooled, W1, b1, g2, b2n, m2, v2, h_ws);
  head2_k<<<1, 128, 0, stream>>>(h_ws, W2, b2, out);
}

// Round 6
// 1641.604 us; speedup vs baseline: 1.4777x; 1.4777x over previous
//
#include <hip/hip_runtime.h>
#include <math.h>

// Problem constants (match reference)
constexpr int N_  = 50000;
constexpr int E_  = 1600000;
constexpr int F   = 64;
constexpr int DEA = 16;
constexpr int LL  = 3;
constexpr int GG  = 64;
constexpr int HH  = 256;
constexpr int OO  = 2;
constexpr int ZIN = 2 * F + DEA;  // 144
#define EPS_ 1e-5f

// ---------- helpers ----------
__device__ __forceinline__ unsigned int fmap(float f) {
  unsigned int u = __float_as_uint(f);
  return (u & 0x80000000u) ? ~u : (u | 0x80000000u);
}
__device__ __forceinline__ float funmap(unsigned int m) {
  return (m & 0x80000000u) ? __uint_as_float(m ^ 0x80000000u)
                           : __uint_as_float(~m);
}

// ---------- per-node linear projections ----------
// Darr[n][k] = (x[n] @ Wf[0:64])[k] + bf[k]   (.x)  and Ws-version (.y)
// Sarr[n][k] = (x[n] @ Wf[64:128])[k]         (.x)  and Ws-version (.y)
__global__ __launch_bounds__(256) void node_linear_k(
    const float* __restrict__ x, const float* __restrict__ Wf,
    const float* __restrict__ bf, const float* __restrict__ Ws,
    const float* __restrict__ bs, float2* __restrict__ Darr,
    float2* __restrict__ Sarr) {
  __shared__ float xs[4][64];
  const int wave = threadIdx.x >> 6, lane = threadIdx.x & 63;
  const int n = blockIdx.x * 4 + wave;  // grid = N/4 exact
  xs[wave][lane] = x[n * 64 + lane];
  __syncthreads();
  float df = 0.f, ds = 0.f, sf = 0.f, ss = 0.f;
#pragma unroll 8
  for (int d = 0; d < 64; ++d) {
    const float xv = xs[wave][d];
    df += xv * Wf[d * 64 + lane];
    sf += xv * Wf[(64 + d) * 64 + lane];
    ds += xv * Ws[d * 64 + lane];
    ss += xv * Ws[(64 + d) * 64 + lane];
  }
  Darr[n * 64 + lane] = make_float2(df + bf[lane], ds + bs[lane]);
  Sarr[n * 64 + lane] = make_float2(sf, ss);
}

// ---------- per-edge message + atomic scatter ----------
// Persistent waves, grid-stride over edges. Weights (16x64 f + 16x64 s) live
// in 32 VGPRs/lane for the whole kernel. Edge index e is wave-uniform ->
// readfirstlane turns src/dst/edge_attr reads into scalar (SMEM) loads.
__global__ __launch_bounds__(256) void edge_msg_k(
    const int* __restrict__ src, const int* __restrict__ dst,
    const float* __restrict__ ea, const float* __restrict__ WfE,
    const float* __restrict__ WsE, const float2* __restrict__ Darr,
    const float2* __restrict__ Sarr, float* __restrict__ agg,
    int nwaves_total) {
  const int lane = threadIdx.x & 63;
  const int wid = blockIdx.x * 4 + (threadIdx.x >> 6);
  // register-resident edge-attr weight columns for this lane
  float wf[DEA], wsr[DEA];
#pragma unroll
  for (int d = 0; d < DEA; ++d) {
    wf[d]  = WfE[d * 64 + lane];
    wsr[d] = WsE[d * 64 + lane];
  }
  for (int e = wid; e < E_; e += nwaves_total) {
    const int eu = __builtin_amdgcn_readfirstlane(e);
    const int s  = src[eu];   // s_load (wave-uniform address)
    const int d0 = dst[eu];   // s_load
    const float2 dv = Darr[d0 * 64 + lane];
    const float2 sv = Sarr[s * 64 + lane];
    float gf = dv.x + sv.x;
    float gs = dv.y + sv.y;
    const float* eap = ea + (size_t)eu * DEA;  // s_load_dwordx* batch
#pragma unroll
    for (int d = 0; d < DEA; ++d) {
      const float av = eap[d];
      gf = fmaf(av, wf[d], gf);
      gs = fmaf(av, wsr[d], gs);
    }
    const float sig = 1.f / (1.f + __expf(-gf));
    const float sp = (gs > 20.f) ? gs : __logf(1.f + __expf(gs));
    atomicAdd(&agg[d0 * 64 + lane], sig * sp);
  }
}

// ---------- BN (inference) + residual ----------
__global__ __launch_bounds__(256) void bn_res_k(
    const float* __restrict__ xin, const float* __restrict__ agg,
    const float* __restrict__ g, const float* __restrict__ b,
    const float* __restrict__ m, const float* __restrict__ v,
    float* __restrict__ xout) {
  const int i = blockIdx.x * 256 + threadIdx.x;  // grid = N*F/256 exact
  const int k = i & 63;
  const float sc = rsqrtf(v[k] + EPS_) * g[k];
  xout[i] = xin[i] + (agg[i] - m[k]) * sc + b[k];
}

// ---------- segment max pool (batch sorted) ----------
__global__ __launch_bounds__(256) void pool_max_k(
    const float* __restrict__ x, const int* __restrict__ batch,
    unsigned int* __restrict__ pooled) {
  const int wave_glob = blockIdx.x * 4 + (threadIdx.x >> 6);
  const int lane = threadIdx.x & 63;
  const int n0 = wave_glob * 32;
  if (n0 >= N_) return;
  const int nend = min(n0 + 32, N_);
  int cur_b = batch[n0];
  float mmax = -INFINITY;
  for (int n = n0; n < nend; ++n) {
    const int b = batch[n];
    if (b != cur_b) {
      atomicMax(&pooled[cur_b * 64 + lane], fmap(mmax));
      cur_b = b;
      mmax = -INFINITY;
    }
    mmax = fmaxf(mmax, x[n * 64 + lane]);
  }
  atomicMax(&pooled[cur_b * 64 + lane], fmap(mmax));
}

// ---------- head: h = BN2(relu(pooled @ W1 + b1)) ----------
__global__ __launch_bounds__(256) void head1_k(
    const unsigned int* __restrict__ pooled, const float* __restrict__ W1,
    const float* __restrict__ b1, const float* __restrict__ g2,
    const float* __restrict__ b2n, const float* __restrict__ m2,
    const float* __restrict__ v2, float* __restrict__ h) {
  __shared__ float p[64];
  const int gidx = blockIdx.x;  // grid = GG
  const int j = threadIdx.x;    // 0..255
  if (j < 64) p[j] = funmap(pooled[gidx * 64 + j]);
  __syncthreads();
  float acc = b1[j];
#pragma unroll 8
  for (int k = 0; k < 64; ++k) acc += p[k] * W1[k * HH + j];
  acc = fmaxf(acc, 0.f);
  acc = (acc - m2[j]) * rsqrtf(v2[j] + EPS_) * g2[j] + b2n[j];
  h[gidx * HH + j] = acc;
}

// ---------- head: out = sigmoid(h @ W2 + b2) ----------
__global__ __launch_bounds__(128) void head2_k(
    const float* __restrict__ h, const float* __restrict__ W2,
    const float* __restrict__ b2, float* __restrict__ out) {
  const int t = threadIdx.x;  // 128 threads
  const int gidx = t >> 1, o = t & 1;
  float acc = b2[o];
#pragma unroll 8
  for (int k = 0; k < HH; ++k) acc += h[gidx * HH + k] * W2[k * OO + o];
  out[gidx * OO + o] = 1.f / (1.f + __expf(-acc));
}

extern "C" void kernel_launch(void* const* d_in, const int* in_sizes, int n_in,
                              void* d_out, int out_size, void* d_ws,
                              size_t ws_size, hipStream_t stream) {
  const float* x    = (const float*)d_in[0];
  const int* ei     = (const int*)d_in[1];
  const float* ea   = (const float*)d_in[2];
  const int* batch  = (const int*)d_in[3];
  const float* Wf   = (const float*)d_in[4];
  const float* bf   = (const float*)d_in[5];
  const float* Ws   = (const float*)d_in[6];
  const float* bs   = (const float*)d_in[7];
  const float* bn_g = (const float*)d_in[8];
  const float* bn_b = (const float*)d_in[9];
  const float* bn_m = (const float*)d_in[10];
  const float* bn_v = (const float*)d_in[11];
  const float* W1   = (const float*)d_in[12];
  const float* b1   = (const float*)d_in[13];
  const float* g2   = (const float*)d_in[14];
  const float* b2n  = (const float*)d_in[15];
  const float* m2   = (const float*)d_in[16];
  const float* v2   = (const float*)d_in[17];
  const float* W2   = (const float*)d_in[18];
  const float* b2   = (const float*)d_in[19];
  float* out = (float*)d_out;

  // workspace layout
  char* ws = (char*)d_ws;
  float2* Darr = (float2*)ws;                          // N*64 float2 (25.6 MB)
  float2* Sarr = Darr + (size_t)N_ * 64;               // N*64 float2 (25.6 MB)
  float* x_cur = (float*)(Sarr + (size_t)N_ * 64);     // N*F   (12.8 MB)
  float* agg   = x_cur + (size_t)N_ * F;               // N*F   (12.8 MB)
  unsigned int* pooled = (unsigned int*)(agg + (size_t)N_ * F);  // G*F
  float* h_ws  = (float*)(pooled + GG * F);            // G*H

  const int* srcp = ei;
  const int* dstp = ei + E_;

  // persistent-wave grid for edge kernel: 2048 blocks x 4 waves = 8192 waves
  constexpr int EDGE_BLOCKS = 2048;
  constexpr int EDGE_WAVES = EDGE_BLOCKS * 4;

  for (int l = 0; l < LL; ++l) {
    const float* xin = (l == 0) ? x : x_cur;
    node_linear_k<<<N_ / 4, 256, 0, stream>>>(
        xin, Wf + (size_t)l * ZIN * F, bf + l * F, Ws + (size_t)l * ZIN * F,
        bs + l * F, Darr, Sarr);
    hipMemsetAsync(agg, 0, (size_t)N_ * F * sizeof(float), stream);
    edge_msg_k<<<EDGE_BLOCKS, 256, 0, stream>>>(
        srcp, dstp, ea, Wf + (size_t)l * ZIN * F + 2 * F * F,
        Ws + (size_t)l * ZIN * F + 2 * F * F, Darr, Sarr, agg, EDGE_WAVES);
    bn_res_k<<<(N_ * F) / 256, 256, 0, stream>>>(
        xin, agg, bn_g + l * F, bn_b + l * F, bn_m + l * F, bn_v + l * F,
        x_cur);
  }
  hipMemsetAsync(pooled, 0, GG * F * sizeof(unsigned int), stream);
  const int nwaves = (N_ + 31) / 32;
  pool_max_k<<<(nwaves + 3) / 4, 256, 0, stream>>>(x_cur, batch, pooled);
  head1_k<<<GG, 256, 0, stream>>>(pooled, W1, b1, g2, b2n, m2, v2, h_ws);
  head2_k<<<1, 128, 0, stream>>>(h_ws, W2, b2, out);
}

// Round 9
// 1499.289 us; speedup vs baseline: 1.6179x; 1.0949x over previous
//
#include <hip/hip_runtime.h>
#include <math.h>

// Problem constants (match reference)
constexpr int N_  = 50000;
constexpr int E_  = 1600000;
constexpr int F   = 64;
constexpr int DEA = 16;
constexpr int LL  = 3;
constexpr int GG  = 64;
constexpr int HH  = 256;
constexpr int OO  = 2;
constexpr int ZIN = 2 * F + DEA;  // 144
#define EPS_ 1e-5f

// ---------- helpers ----------
__device__ __forceinline__ unsigned int fmap(float f) {
  unsigned int u = __float_as_uint(f);
  return (u & 0x80000000u) ? ~u : (u | 0x80000000u);
}
__device__ __forceinline__ float funmap(unsigned int m) {
  return (m & 0x80000000u) ? __uint_as_float(m ^ 0x80000000u)
                           : __uint_as_float(~m);
}
// round-to-nearest-even f32 -> bf16 (as uint16 in low bits)
__device__ __forceinline__ unsigned f2bf(float f) {
  unsigned u = __float_as_uint(f);
  return (u + 0x7FFFu + ((u >> 16) & 1u)) >> 16;
}

// ---------- per-node linear projections ----------
// Darr[n][k] = ((x[n] @ Wf[0:64])[k] + bf[k], same for Ws)   [f32 float2]
// SarrP[n][k] = pack_bf16((x[n] @ Wf[64:128])[k], Ws-version) [bf16x2]
__global__ __launch_bounds__(256) void node_linear_k(
    const float* __restrict__ x, const float* __restrict__ Wf,
    const float* __restrict__ bf, const float* __restrict__ Ws,
    const float* __restrict__ bs, float2* __restrict__ Darr,
    unsigned* __restrict__ SarrP) {
  __shared__ float xs[4][64];
  const int wave = threadIdx.x >> 6, lane = threadIdx.x & 63;
  const int n = blockIdx.x * 4 + wave;  // grid = N/4 exact
  xs[wave][lane] = x[n * 64 + lane];
  __syncthreads();
  float df = 0.f, ds = 0.f, sf = 0.f, ss = 0.f;
#pragma unroll 8
  for (int d = 0; d < 64; ++d) {
    const float xv = xs[wave][d];
    df += xv * Wf[d * 64 + lane];
    sf += xv * Wf[(64 + d) * 64 + lane];
    ds += xv * Ws[d * 64 + lane];
    ss += xv * Ws[(64 + d) * 64 + lane];
  }
  Darr[n * 64 + lane] = make_float2(df + bf[lane], ds + bs[lane]);
  SarrP[n * 64 + lane] = f2bf(sf) | (f2bf(ss) << 16);
}

// ---------- CSR build: histogram / scan / scatter ----------
__global__ __launch_bounds__(256) void hist_k(const int* __restrict__ dst,
                                              int* __restrict__ cnt) {
  const int e = blockIdx.x * 256 + threadIdx.x;  // grid = E/256 exact
  atomicAdd(&cnt[dst[e]], 1);
}

constexpr int SCAN_T = 1024;
constexpr int CHUNK = 49;  // 1024*49 = 50176 >= N_+1

__global__ __launch_bounds__(SCAN_T) void scan_k(const int* __restrict__ cnt,
                                                 int* __restrict__ rowptr,
                                                 int* __restrict__ cursor) {
  __shared__ int s[SCAN_T];
  const int t = threadIdx.x;
  int partial = 0;
  for (int j = 0; j < CHUNK; ++j) {
    const int idx = t * CHUNK + j;
    if (idx < N_) partial += cnt[idx];
  }
  s[t] = partial;
  __syncthreads();
  for (int off = 1; off < SCAN_T; off <<= 1) {
    int v = (t >= off) ? s[t - off] : 0;
    __syncthreads();
    s[t] += v;
    __syncthreads();
  }
  int run = s[t] - partial;  // exclusive prefix
  for (int j = 0; j < CHUNK; ++j) {
    const int idx = t * CHUNK + j;
    if (idx < N_) {
      rowptr[idx] = run;
      cursor[idx] = run;
      run += cnt[idx];
    } else if (idx == N_) {
      rowptr[idx] = run;  // == E_
    }
  }
}

__global__ __launch_bounds__(256) void scatter_k(
    const int* __restrict__ src, const int* __restrict__ dst,
    int* __restrict__ cursor, int* __restrict__ eid,
    int* __restrict__ csr_src) {
  const int e = blockIdx.x * 256 + threadIdx.x;  // grid = E/256 exact
  const int d = dst[e];
  const int pos = atomicAdd(&cursor[d], 1);
  eid[pos] = e;
  csr_src[pos] = src[e];
}

// ---------- per-node edge aggregation + fused BN + residual ----------
// One wave per dst node (grid-stride). Edge-attr weight tiles live in 32
// VGPRs/lane. All per-edge index/attr reads are wave-uniform -> scalar loads.
__global__ __launch_bounds__(256) void edge_agg_k(
    const int* __restrict__ rowptr, const int* __restrict__ eid,
    const int* __restrict__ csr_src, const float* __restrict__ ea,
    const float* __restrict__ WfE, const float* __restrict__ WsE,
    const float2* __restrict__ Darr, const unsigned* __restrict__ SarrP,
    const float* __restrict__ xin, const float* __restrict__ g,
    const float* __restrict__ b, const float* __restrict__ m,
    const float* __restrict__ v, float* __restrict__ xout,
    int nwaves_total) {
  const int lane = threadIdx.x & 63;
  const int wid = blockIdx.x * 4 + (threadIdx.x >> 6);
  float wf[DEA], wsr[DEA];
#pragma unroll
  for (int d = 0; d < DEA; ++d) {
    wf[d]  = WfE[d * 64 + lane];
    wsr[d] = WsE[d * 64 + lane];
  }
  const float bnm = m[lane];
  const float bnsc = rsqrtf(v[lane] + EPS_) * g[lane];
  const float bnb = b[lane];
  for (int n = wid; n < N_; n += nwaves_total) {
    const int nu = __builtin_amdgcn_readfirstlane(n);
    const int r0 = rowptr[nu], r1 = rowptr[nu + 1];  // s_load
    const float2 dv = Darr[nu * 64 + lane];
    float acc = 0.f;
    for (int i = r0; i < r1; ++i) {
      const int e = eid[i];       // s_load (uniform)
      const int s = csr_src[i];   // s_load (uniform, parallel with eid)
      const unsigned p = SarrP[s * 64 + lane];  // 256B coalesced gather
      float gf = dv.x + __uint_as_float(p << 16);
      float gs = dv.y + __uint_as_float(p & 0xFFFF0000u);
      const float* eap = ea + (size_t)e * DEA;  // s_load_dwordx8 x2
#pragma unroll
      for (int d = 0; d < DEA; ++d) {
        const float av = eap[d];
        gf = fmaf(av, wf[d], gf);
        gs = fmaf(av, wsr[d], gs);
      }
      const float sig = 1.f / (1.f + __expf(-gf));
      // branchless stable softplus
      const float sp = fmaxf(gs, 0.f) + __logf(1.f + __expf(-fabsf(gs)));
      acc = fmaf(sig, sp, acc);
    }
    xout[nu * 64 + lane] = xin[nu * 64 + lane] + (acc - bnm) * bnsc + bnb;
  }
}

// ---------- segment max pool (batch sorted) ----------
__global__ __launch_bounds__(256) void pool_max_k(
    const float* __restrict__ x, const int* __restrict__ batch,
    unsigned int* __restrict__ pooled) {
  const int wave_glob = blockIdx.x * 4 + (threadIdx.x >> 6);
  const int lane = threadIdx.x & 63;
  const int n0 = wave_glob * 32;
  if (n0 >= N_) return;
  const int nend = min(n0 + 32, N_);
  int cur_b = batch[n0];
  float mmax = -INFINITY;
  for (int n = n0; n < nend; ++n) {
    const int b = batch[n];
    if (b != cur_b) {
      atomicMax(&pooled[cur_b * 64 + lane], fmap(mmax));
      cur_b = b;
      mmax = -INFINITY;
    }
    mmax = fmaxf(mmax, x[n * 64 + lane]);
  }
  atomicMax(&pooled[cur_b * 64 + lane], fmap(mmax));
}

// ---------- head: h = BN2(relu(pooled @ W1 + b1)) ----------
__global__ __launch_bounds__(256) void head1_k(
    const unsigned int* __restrict__ pooled, const float* __restrict__ W1,
    const float* __restrict__ b1, const float* __restrict__ g2,
    const float* __restrict__ b2n, const float* __restrict__ m2,
    const float* __restrict__ v2, float* __restrict__ h) {
  __shared__ float p[64];
  const int gidx = blockIdx.x;  // grid = GG
  const int j = threadIdx.x;    // 0..255
  if (j < 64) p[j] = funmap(pooled[gidx * 64 + j]);
  __syncthreads();
  float acc = b1[j];
#pragma unroll 8
  for (int k = 0; k < 64; ++k) acc += p[k] * W1[k * HH + j];
  acc = fmaxf(acc, 0.f);
  acc = (acc - m2[j]) * rsqrtf(v2[j] + EPS_) * g2[j] + b2n[j];
  h[gidx * HH + j] = acc;
}

// ---------- head: out = sigmoid(h @ W2 + b2) ----------
__global__ __launch_bounds__(128) void head2_k(
    const float* __restrict__ h, const float* __restrict__ W2,
    const float* __restrict__ b2, float* __restrict__ out) {
  const int t = threadIdx.x;  // 128 threads
  const int gidx = t >> 1, o = t & 1;
  float acc = b2[o];
#pragma unroll 8
  for (int k = 0; k < HH; ++k) acc += h[gidx * HH + k] * W2[k * OO + o];
  out[gidx * OO + o] = 1.f / (1.f + __expf(-acc));
}

extern "C" void kernel_launch(void* const* d_in, const int* in_sizes, int n_in,
                              void* d_out, int out_size, void* d_ws,
                              size_t ws_size, hipStream_t stream) {
  const float* x    = (const float*)d_in[0];
  const int* ei     = (const int*)d_in[1];
  const float* ea   = (const float*)d_in[2];
  const int* batch  = (const int*)d_in[3];
  const float* Wf   = (const float*)d_in[4];
  const float* bf   = (const float*)d_in[5];
  const float* Ws   = (const float*)d_in[6];
  const float* bs   = (const float*)d_in[7];
  const float* bn_g = (const float*)d_in[8];
  const float* bn_b = (const float*)d_in[9];
  const float* bn_m = (const float*)d_in[10];
  const float* bn_v = (const float*)d_in[11];
  const float* W1   = (const float*)d_in[12];
  const float* b1   = (const float*)d_in[13];
  const float* g2   = (const float*)d_in[14];
  const float* b2n  = (const float*)d_in[15];
  const float* m2   = (const float*)d_in[16];
  const float* v2   = (const float*)d_in[17];
  const float* W2   = (const float*)d_in[18];
  const float* b2   = (const float*)d_in[19];
  float* out = (float*)d_out;

  // workspace layout
  char* ws = (char*)d_ws;
  float2* Darr   = (float2*)ws;                        // N*64 float2 (25.6 MB)
  unsigned* SarrP = (unsigned*)(Darr + (size_t)N_ * 64);  // N*64 u32 (12.8 MB)
  float* x_cur   = (float*)(SarrP + (size_t)N_ * 64);  // N*F (12.8 MB)
  int* cnt       = (int*)(x_cur + (size_t)N_ * F);     // N (200 KB)
  int* rowptr    = cnt + N_;                           // N+1
  int* cursor    = rowptr + (N_ + 1);                  // N+1
  int* eid       = cursor + (N_ + 1);                  // E (6.4 MB)
  int* csr_src   = eid + E_;                           // E (6.4 MB)
  unsigned int* pooled = (unsigned int*)(csr_src + E_);  // G*F
  float* h_ws    = (float*)(pooled + GG * F);          // G*H

  const int* srcp = ei;
  const int* dstp = ei + E_;

  constexpr int EDGE_BLOCKS = 2048;
  constexpr int EDGE_WAVES = EDGE_BLOCKS * 4;

  // ---- CSR build (once per call; reused across the 3 layers) ----
  hipMemsetAsync(cnt, 0, N_ * sizeof(int), stream);
  hist_k<<<E_ / 256, 256, 0, stream>>>(dstp, cnt);
  scan_k<<<1, SCAN_T, 0, stream>>>(cnt, rowptr, cursor);
  scatter_k<<<E_ / 256, 256, 0, stream>>>(srcp, dstp, cursor, eid, csr_src);

  for (int l = 0; l < LL; ++l) {
    const float* xin = (l == 0) ? x : x_cur;
    node_linear_k<<<N_ / 4, 256, 0, stream>>>(
        xin, Wf + (size_t)l * ZIN * F, bf + l * F, Ws + (size_t)l * ZIN * F,
        bs + l * F, Darr, SarrP);
    edge_agg_k<<<EDGE_BLOCKS, 256, 0, stream>>>(
        rowptr, eid, csr_src, ea, Wf + (size_t)l * ZIN * F + 2 * F * F,
        Ws + (size_t)l * ZIN * F + 2 * F * F, Darr, SarrP, xin,
        bn_g + l * F, bn_b + l * F, bn_m + l * F, bn_v + l * F, x_cur,
        EDGE_WAVES);
  }
  hipMemsetAsync(pooled, 0, GG * F * sizeof(unsigned int), stream);
  const int nwaves = (N_ + 31) / 32;
  pool_max_k<<<(nwaves + 3) / 4, 256, 0, stream>>>(x_cur, batch, pooled);
  head1_k<<<GG, 256, 0, stream>>>(pooled, W1, b1, g2, b2n, m2, v2, h_ws);
  head2_k<<<1, 128, 0, stream>>>(h_ws, W2, b2, out);
}

// Round 10
// 1394.799 us; speedup vs baseline: 1.7391x; 1.0749x over previous
//
#include <hip/hip_runtime.h>
#include <math.h>

// Problem constants (match reference)
constexpr int N_  = 50000;
constexpr int E_  = 1600000;
constexpr int F   = 64;
constexpr int DEA = 16;
constexpr int LL  = 3;
constexpr int GG  = 64;
constexpr int HH  = 256;
constexpr int OO  = 2;
constexpr int ZIN = 2 * F + DEA;  // 144
#define EPS_ 1e-5f

// ---------- helpers ----------
__device__ __forceinline__ unsigned int fmap(float f) {
  unsigned int u = __float_as_uint(f);
  return (u & 0x80000000u) ? ~u : (u | 0x80000000u);
}
__device__ __forceinline__ float funmap(unsigned int m) {
  return (m & 0x80000000u) ? __uint_as_float(m ^ 0x80000000u)
                           : __uint_as_float(~m);
}
// round-to-nearest-even f32 -> bf16 (as uint16 in low bits)
__device__ __forceinline__ unsigned f2bf(float f) {
  unsigned u = __float_as_uint(f);
  return (u + 0x7FFFu + ((u >> 16) & 1u)) >> 16;
}

// ---------- per-node linear projections ----------
// Darr[n][k] = ((x[n] @ Wf[0:64])[k] + bf[k], same for Ws)   [f32 float2]
// SarrP[n][k] = pack_bf16((x[n] @ Wf[64:128])[k], Ws-version) [bf16x2]
__global__ __launch_bounds__(256) void node_linear_k(
    const float* __restrict__ x, const float* __restrict__ Wf,
    const float* __restrict__ bf, const float* __restrict__ Ws,
    const float* __restrict__ bs, float2* __restrict__ Darr,
    unsigned* __restrict__ SarrP) {
  __shared__ float xs[4][64];
  const int wave = threadIdx.x >> 6, lane = threadIdx.x & 63;
  const int n = blockIdx.x * 4 + wave;  // grid = N/4 exact
  xs[wave][lane] = x[n * 64 + lane];
  __syncthreads();
  float df = 0.f, ds = 0.f, sf = 0.f, ss = 0.f;
#pragma unroll 8
  for (int d = 0; d < 64; ++d) {
    const float xv = xs[wave][d];
    df += xv * Wf[d * 64 + lane];
    sf += xv * Wf[(64 + d) * 64 + lane];
    ds += xv * Ws[d * 64 + lane];
    ss += xv * Ws[(64 + d) * 64 + lane];
  }
  Darr[n * 64 + lane] = make_float2(df + bf[lane], ds + bs[lane]);
  SarrP[n * 64 + lane] = f2bf(sf) | (f2bf(ss) << 16);
}

// ---------- CSR build: histogram / scan / scatter ----------
__global__ __launch_bounds__(256) void hist_k(const int* __restrict__ dst,
                                              int* __restrict__ cnt) {
  const int e = blockIdx.x * 256 + threadIdx.x;  // grid = E/256 exact
  atomicAdd(&cnt[dst[e]], 1);
}

constexpr int SCAN_T = 1024;
constexpr int CHUNK = 52;  // 13 int4s; 1024*52 = 53248 >= N_+1

__global__ __launch_bounds__(SCAN_T) void scan_k(const int* __restrict__ cnt,
                                                 int* __restrict__ rowptr,
                                                 int* __restrict__ cursor) {
  __shared__ int s[SCAN_T];
  const int t = threadIdx.x;
  int vals[CHUNK];
  const int base = t * CHUNK;
  // vectorized loads (reads past N_ stay inside ws; masked below)
#pragma unroll
  for (int j = 0; j < CHUNK / 4; ++j) {
    const int4 v = *(const int4*)(cnt + base + j * 4);
    vals[j * 4 + 0] = v.x;
    vals[j * 4 + 1] = v.y;
    vals[j * 4 + 2] = v.z;
    vals[j * 4 + 3] = v.w;
  }
  int partial = 0;
#pragma unroll
  for (int j = 0; j < CHUNK; ++j)
    if (base + j < N_) partial += vals[j];
  s[t] = partial;
  __syncthreads();
  for (int off = 1; off < SCAN_T; off <<= 1) {
    int v = (t >= off) ? s[t - off] : 0;
    __syncthreads();
    s[t] += v;
    __syncthreads();
  }
  int run = s[t] - partial;  // exclusive prefix
#pragma unroll
  for (int j = 0; j < CHUNK; ++j) {
    const int idx = base + j;
    if (idx < N_) {
      rowptr[idx] = run;
      cursor[idx] = run;
      run += vals[j];
    } else if (idx == N_) {
      rowptr[idx] = run;  // == E_
    }
  }
}

// scatter edges into CSR order; also pre-gather edge_attr into CSR order
__global__ __launch_bounds__(256) void scatter_k(
    const int* __restrict__ src, const int* __restrict__ dst,
    const float* __restrict__ ea, int* __restrict__ cursor,
    int* __restrict__ csr_src, float* __restrict__ ea_csr) {
  const int e = blockIdx.x * 256 + threadIdx.x;  // grid = E/256 exact
  const int d = dst[e];
  const int pos = atomicAdd(&cursor[d], 1);
  csr_src[pos] = src[e];
  const float4* s4 = (const float4*)(ea + (size_t)e * DEA);
  float4* d4 = (float4*)(ea_csr + (size_t)pos * DEA);
  d4[0] = s4[0];
  d4[1] = s4[1];
  d4[2] = s4[2];
  d4[3] = s4[3];
}

// ---------- per-node edge aggregation + fused BN + residual ----------
// One wave per dst node (grid-stride). Edge-attr weight tiles held in VGPRs
// (asm-opaqued so the compiler cannot rematerialize them in-loop). All
// per-edge index/attr reads are wave-uniform contiguous -> scalar loads.
__global__ __launch_bounds__(256) void edge_agg_k(
    const int* __restrict__ rowptr, const int* __restrict__ csr_src,
    const float* __restrict__ ea_csr, const float* __restrict__ WfE,
    const float* __restrict__ WsE, const float2* __restrict__ Darr,
    const unsigned* __restrict__ SarrP, const float* __restrict__ xin,
    const float* __restrict__ g, const float* __restrict__ b,
    const float* __restrict__ m, const float* __restrict__ v,
    float* __restrict__ xout, int nwaves_total) {
  const int lane = threadIdx.x & 63;
  const int wid = blockIdx.x * 4 + (threadIdx.x >> 6);
  float2 w[DEA];
#pragma unroll
  for (int d = 0; d < DEA; ++d)
    w[d] = make_float2(WfE[d * 64 + lane], WsE[d * 64 + lane]);
  // force register residency: asm is a def point -> no rematerialization
#pragma unroll
  for (int d = 0; d < DEA; ++d)
    asm volatile("" : "+v"(w[d].x), "+v"(w[d].y));
  const float bnm = m[lane];
  const float bnsc = rsqrtf(v[lane] + EPS_) * g[lane];
  const float bnb = b[lane];
  for (int n = wid; n < N_; n += nwaves_total) {
    const int nu = __builtin_amdgcn_readfirstlane(n);
    const int r0 = rowptr[nu], r1 = rowptr[nu + 1];  // s_load
    const float2 dv = Darr[nu * 64 + lane];
    float acc = 0.f;
    if (r0 < r1) {
      unsigned p_cur = SarrP[(size_t)csr_src[r0] * 64 + lane];
      for (int i = r0; i < r1; ++i) {
        unsigned p_next = 0;
        if (i + 1 < r1)  // wave-uniform branch; prefetch next src row
          p_next = SarrP[(size_t)csr_src[i + 1] * 64 + lane];
        const float* eap = ea_csr + (size_t)i * DEA;  // contiguous s_loads
        float gf = dv.x + __uint_as_float(p_cur << 16);
        float gs = dv.y + __uint_as_float(p_cur & 0xFFFF0000u);
#pragma unroll
        for (int d = 0; d < DEA; ++d) {
          const float av = eap[d];
          gf = fmaf(av, w[d].x, gf);
          gs = fmaf(av, w[d].y, gs);
        }
        const float sig = 1.f / (1.f + __expf(-gf));
        // branchless stable softplus
        const float sp = fmaxf(gs, 0.f) + __logf(1.f + __expf(-fabsf(gs)));
        acc = fmaf(sig, sp, acc);
        p_cur = p_next;
      }
    }
    xout[nu * 64 + lane] = xin[nu * 64 + lane] + (acc - bnm) * bnsc + bnb;
  }
}

// ---------- segment max pool (batch sorted) ----------
__global__ __launch_bounds__(256) void pool_max_k(
    const float* __restrict__ x, const int* __restrict__ batch,
    unsigned int* __restrict__ pooled) {
  const int wave_glob = blockIdx.x * 4 + (threadIdx.x >> 6);
  const int lane = threadIdx.x & 63;
  const int n0 = wave_glob * 32;
  if (n0 >= N_) return;
  const int nend = min(n0 + 32, N_);
  int cur_b = batch[n0];
  float mmax = -INFINITY;
  for (int n = n0; n < nend; ++n) {
    const int b = batch[n];
    if (b != cur_b) {
      atomicMax(&pooled[cur_b * 64 + lane], fmap(mmax));
      cur_b = b;
      mmax = -INFINITY;
    }
    mmax = fmaxf(mmax, x[n * 64 + lane]);
  }
  atomicMax(&pooled[cur_b * 64 + lane], fmap(mmax));
}

// ---------- head: h = BN2(relu(pooled @ W1 + b1)) ----------
__global__ __launch_bounds__(256) void head1_k(
    const unsigned int* __restrict__ pooled, const float* __restrict__ W1,
    const float* __restrict__ b1, const float* __restrict__ g2,
    const float* __restrict__ b2n, const float* __restrict__ m2,
    const float* __restrict__ v2, float* __restrict__ h) {
  __shared__ float p[64];
  const int gidx = blockIdx.x;  // grid = GG
  const int j = threadIdx.x;    // 0..255
  if (j < 64) p[j] = funmap(pooled[gidx * 64 + j]);
  __syncthreads();
  float acc = b1[j];
#pragma unroll 8
  for (int k = 0; k < 64; ++k) acc += p[k] * W1[k * HH + j];
  acc = fmaxf(acc, 0.f);
  acc = (acc - m2[j]) * rsqrtf(v2[j] + EPS_) * g2[j] + b2n[j];
  h[gidx * HH + j] = acc;
}

// ---------- head: out = sigmoid(h @ W2 + b2) ----------
__global__ __launch_bounds__(128) void head2_k(
    const float* __restrict__ h, const float* __restrict__ W2,
    const float* __restrict__ b2, float* __restrict__ out) {
  const int t = threadIdx.x;  // 128 threads
  const int gidx = t >> 1, o = t & 1;
  float acc = b2[o];
#pragma unroll 8
  for (int k = 0; k < HH; ++k) acc += h[gidx * HH + k] * W2[k * OO + o];
  out[gidx * OO + o] = 1.f / (1.f + __expf(-acc));
}

extern "C" void kernel_launch(void* const* d_in, const int* in_sizes, int n_in,
                              void* d_out, int out_size, void* d_ws,
                              size_t ws_size, hipStream_t stream) {
  const float* x    = (const float*)d_in[0];
  const int* ei     = (const int*)d_in[1];
  const float* ea   = (const float*)d_in[2];
  const int* batch  = (const int*)d_in[3];
  const float* Wf   = (const float*)d_in[4];
  const float* bf   = (const float*)d_in[5];
  const float* Ws   = (const float*)d_in[6];
  const float* bs   = (const float*)d_in[7];
  const float* bn_g = (const float*)d_in[8];
  const float* bn_b = (const float*)d_in[9];
  const float* bn_m = (const float*)d_in[10];
  const float* bn_v = (const float*)d_in[11];
  const float* W1   = (const float*)d_in[12];
  const float* b1   = (const float*)d_in[13];
  const float* g2   = (const float*)d_in[14];
  const float* b2n  = (const float*)d_in[15];
  const float* m2   = (const float*)d_in[16];
  const float* v2   = (const float*)d_in[17];
  const float* W2   = (const float*)d_in[18];
  const float* b2   = (const float*)d_in[19];
  float* out = (float*)d_out;

  // workspace layout (~161 MB)
  char* ws = (char*)d_ws;
  float2* Darr   = (float2*)ws;                        // N*64 float2 (25.6 MB)
  unsigned* SarrP = (unsigned*)(Darr + (size_t)N_ * 64);  // N*64 u32 (12.8 MB)
  float* x_cur   = (float*)(SarrP + (size_t)N_ * 64);  // N*F (12.8 MB)
  int* cnt       = (int*)(x_cur + (size_t)N_ * F);     // N (200 KB)
  int* rowptr    = cnt + N_;                           // N+1
  int* cursor    = rowptr + (N_ + 4);                  // N+1 (padded)
  int* csr_src   = cursor + (N_ + 4);                  // E (6.4 MB)
  float* ea_csr  = (float*)(csr_src + E_);             // E*16 f32 (102.4 MB)
  unsigned int* pooled = (unsigned int*)(ea_csr + (size_t)E_ * DEA);  // G*F
  float* h_ws    = (float*)(pooled + GG * F);          // G*H

  const int* srcp = ei;
  const int* dstp = ei + E_;

  constexpr int EDGE_BLOCKS = 2048;
  constexpr int EDGE_WAVES = EDGE_BLOCKS * 4;

  // ---- CSR build (once per call; reused across the 3 layers) ----
  hipMemsetAsync(cnt, 0, N_ * sizeof(int), stream);
  hist_k<<<E_ / 256, 256, 0, stream>>>(dstp, cnt);
  scan_k<<<1, SCAN_T, 0, stream>>>(cnt, rowptr, cursor);
  scatter_k<<<E_ / 256, 256, 0, stream>>>(srcp, dstp, ea, cursor, csr_src,
                                          ea_csr);

  for (int l = 0; l < LL; ++l) {
    const float* xin = (l == 0) ? x : x_cur;
    node_linear_k<<<N_ / 4, 256, 0, stream>>>(
        xin, Wf + (size_t)l * ZIN * F, bf + l * F, Ws + (size_t)l * ZIN * F,
        bs + l * F, Darr, SarrP);
    edge_agg_k<<<EDGE_BLOCKS, 256, 0, stream>>>(
        rowptr, csr_src, ea_csr, Wf + (size_t)l * ZIN * F + 2 * F * F,
        Ws + (size_t)l * ZIN * F + 2 * F * F, Darr, SarrP, xin,
        bn_g + l * F, bn_b + l * F, bn_m + l * F, bn_v + l * F, x_cur,
        EDGE_WAVES);
  }
  hipMemsetAsync(pooled, 0, GG * F * sizeof(unsigned int), stream);
  const int nwaves = (N_ + 31) / 32;
  pool_max_k<<<(nwaves + 3) / 4, 256, 0, stream>>>(x_cur, batch, pooled);
  head1_k<<<GG, 256, 0, stream>>>(pooled, W1, b1, g2, b2n, m2, v2, h_ws);
  head2_k<<<1, 128, 0, stream>>>(h_ws, W2, b2, out);
}

// Round 13
// 1217.602 us; speedup vs baseline: 1.9922x; 1.1455x over previous
//
#include <hip/hip_runtime.h>
#include <math.h>

// Problem constants (match reference)
constexpr int N_  = 50000;
constexpr int E_  = 1600000;
constexpr int F   = 64;
constexpr int DEA = 16;
constexpr int LL  = 3;
constexpr int GG  = 64;
constexpr int HH  = 256;
constexpr int OO  = 2;
constexpr int ZIN = 2 * F + DEA;  // 144
#define EPS_ 1e-5f

typedef float v2f __attribute__((ext_vector_type(2)));

#define LOG2E_ 1.44269504f
#define LN2_ 0.69314718f

// ---------- helpers ----------
__device__ __forceinline__ unsigned int fmap(float f) {
  unsigned int u = __float_as_uint(f);
  return (u & 0x80000000u) ? ~u : (u | 0x80000000u);
}
__device__ __forceinline__ float funmap(unsigned int m) {
  return (m & 0x80000000u) ? __uint_as_float(m ^ 0x80000000u)
                           : __uint_as_float(~m);
}
// round-to-nearest-even f32 -> bf16 (as uint16 in low bits)
__device__ __forceinline__ unsigned f2bf(float f) {
  unsigned u = __float_as_uint(f);
  return (u + 0x7FFFu + ((u >> 16) & 1u)) >> 16;
}

// ---------- per-node linear projections ----------
// Darr[n][k] = ((x[n] @ Wf[0:64])[k] + bf[k], same for Ws)   [f32 float2]
// SarrP[n][k] = pack_bf16((x[n] @ Wf[64:128])[k], Ws-version) [bf16x2]
__global__ __launch_bounds__(256) void node_linear_k(
    const float* __restrict__ x, const float* __restrict__ Wf,
    const float* __restrict__ bf, const float* __restrict__ Ws,
    const float* __restrict__ bs, float2* __restrict__ Darr,
    unsigned* __restrict__ SarrP) {
  __shared__ float xs[4][64];
  const int wave = threadIdx.x >> 6, lane = threadIdx.x & 63;
  const int n = blockIdx.x * 4 + wave;  // grid = N/4 exact
  xs[wave][lane] = x[n * 64 + lane];
  __syncthreads();
  float df = 0.f, ds = 0.f, sf = 0.f, ss = 0.f;
#pragma unroll 8
  for (int d = 0; d < 64; ++d) {
    const float xv = xs[wave][d];
    df += xv * Wf[d * 64 + lane];
    sf += xv * Wf[(64 + d) * 64 + lane];
    ds += xv * Ws[d * 64 + lane];
    ss += xv * Ws[(64 + d) * 64 + lane];
  }
  Darr[n * 64 + lane] = make_float2(df + bf[lane], ds + bs[lane]);
  SarrP[n * 64 + lane] = f2bf(sf) | (f2bf(ss) << 16);
}

// ---------- CSR build: histogram / scan / scatter ----------
__global__ __launch_bounds__(256) void hist_k(const int* __restrict__ dst,
                                              int* __restrict__ cnt) {
  const int e = blockIdx.x * 256 + threadIdx.x;  // grid = E/256 exact
  atomicAdd(&cnt[dst[e]], 1);
}

constexpr int SCAN_T = 1024;
constexpr int CHUNK = 52;  // 13 int4s; 1024*52 = 53248 >= N_+1

__global__ __launch_bounds__(SCAN_T) void scan_k(const int* __restrict__ cnt,
                                                 int* __restrict__ rowptr,
                                                 int* __restrict__ cursor) {
  __shared__ int s[SCAN_T];
  const int t = threadIdx.x;
  int vals[CHUNK];
  const int base = t * CHUNK;
  // vectorized loads (reads past N_ stay inside ws; masked below)
#pragma unroll
  for (int j = 0; j < CHUNK / 4; ++j) {
    const int4 v = *(const int4*)(cnt + base + j * 4);
    vals[j * 4 + 0] = v.x;
    vals[j * 4 + 1] = v.y;
    vals[j * 4 + 2] = v.z;
    vals[j * 4 + 3] = v.w;
  }
  int partial = 0;
#pragma unroll
  for (int j = 0; j < CHUNK; ++j)
    if (base + j < N_) partial += vals[j];
  s[t] = partial;
  __syncthreads();
  for (int off = 1; off < SCAN_T; off <<= 1) {
    int v = (t >= off) ? s[t - off] : 0;
    __syncthreads();
    s[t] += v;
    __syncthreads();
  }
  int run = s[t] - partial;  // exclusive prefix
#pragma unroll
  for (int j = 0; j < CHUNK; ++j) {
    const int idx = base + j;
    if (idx < N_) {
      rowptr[idx] = run;
      cursor[idx] = run;
      run += vals[j];
    } else if (idx == N_) {
      rowptr[idx] = run;  // == E_
    }
  }
}

// scatter edges into CSR order; also pre-gather edge_attr into CSR order
__global__ __launch_bounds__(256) void scatter_k(
    const int* __restrict__ src, const int* __restrict__ dst,
    const float* __restrict__ ea, int* __restrict__ cursor,
    int* __restrict__ csr_src, float* __restrict__ ea_csr) {
  const int e = blockIdx.x * 256 + threadIdx.x;  // grid = E/256 exact
  const int d = dst[e];
  const int pos = atomicAdd(&cursor[d], 1);
  csr_src[pos] = src[e];
  const float4* s4 = (const float4*)(ea + (size_t)e * DEA);
  float4* d4 = (float4*)(ea_csr + (size_t)pos * DEA);
  d4[0] = s4[0];
  d4[1] = s4[1];
  d4[2] = s4[2];
  d4[3] = s4[3];
}

// ---------- per-node edge aggregation + fused BN + residual ----------
// One wave per dst node (grid-stride). Weights in VGPRs (asm-pinned, packed
// as v2f for v_pk_fma). Per-edge index/attr reads readfirstlane'd -> SMEM.
__global__ __launch_bounds__(256) void edge_agg_k(
    const int* __restrict__ rowptr, const int* __restrict__ csr_src,
    const float* __restrict__ ea_csr, const float* __restrict__ WfE,
    const float* __restrict__ WsE, const float2* __restrict__ Darr,
    const unsigned* __restrict__ SarrP, const float* __restrict__ xin,
    const float* __restrict__ g, const float* __restrict__ b,
    const float* __restrict__ m, const float* __restrict__ v,
    float* __restrict__ xout, int nwaves_total) {
  const int lane = threadIdx.x & 63;
  const int wid = blockIdx.x * 4 + (threadIdx.x >> 6);
  v2f w[DEA];
#pragma unroll
  for (int d = 0; d < DEA; ++d) {
    w[d].x = WfE[d * 64 + lane];
    w[d].y = WsE[d * 64 + lane];
  }
  // pin in VGPRs: asm is a def point -> no rematerialization in-loop
#pragma unroll
  for (int d = 0; d < DEA; ++d) asm volatile("" : "+v"(w[d]));
  const float bnm = m[lane];
  const float bnsc = rsqrtf(v[lane] + EPS_) * g[lane];
  const float bnb = b[lane];
  for (int n = wid; n < N_; n += nwaves_total) {
    const int nu = __builtin_amdgcn_readfirstlane(n);
    const int r0 = rowptr[nu], r1 = rowptr[nu + 1];  // s_load
    const float2 dvl = Darr[nu * 64 + lane];
    const v2f dv = {dvl.x, dvl.y};
    float acc = 0.f;
    if (r0 < r1) {
      unsigned p_cur = SarrP[(size_t)csr_src[r0] * 64 + lane];
      for (int i = r0; i < r1; ++i) {
        const int iu = __builtin_amdgcn_readfirstlane(i);
        const int inx = (iu + 1 < r1) ? iu + 1 : iu;  // scalar cselect
        const unsigned p_next = SarrP[(size_t)csr_src[inx] * 64 + lane];
        const float* eap = ea_csr + (size_t)iu * DEA;  // scalar s_loads
        v2f gv = dv;
        gv.x += __uint_as_float(p_cur << 16);
        gv.y += __uint_as_float(p_cur & 0xFFFF0000u);
#pragma unroll
        for (int d = 0; d < DEA; ++d) gv += eap[d] * w[d];  // v_pk_fma_f32
        // fast sigmoid: rcp(1 + 2^(-gf*log2e))
        const float sig = __builtin_amdgcn_rcpf(
            1.f + __builtin_amdgcn_exp2f(gv.x * -LOG2E_));
        // fast stable softplus: max(gs,0) + ln2*log2(1 + 2^(-|gs|*log2e))
        const float t = __builtin_amdgcn_exp2f(-fabsf(gv.y) * LOG2E_);
        const float sp =
            fmaxf(gv.y, 0.f) + LN2_ * __builtin_amdgcn_logf(1.f + t);
        acc = fmaf(sig, sp, acc);
        p_cur = p_next;
      }
    }
    xout[nu * 64 + lane] = xin[nu * 64 + lane] + (acc - bnm) * bnsc + bnb;
  }
}

// ---------- segment max pool (batch sorted) ----------
__global__ __launch_bounds__(256) void pool_max_k(
    const float* __restrict__ x, const int* __restrict__ batch,
    unsigned int* __restrict__ pooled) {
  const int wave_glob = blockIdx.x * 4 + (threadIdx.x >> 6);
  const int lane = threadIdx.x & 63;
  const int n0 = wave_glob * 32;
  if (n0 >= N_) return;
  const int nend = min(n0 + 32, N_);
  int cur_b = batch[n0];
  float mmax = -INFINITY;
  for (int n = n0; n < nend; ++n) {
    const int b = batch[n];
    if (b != cur_b) {
      atomicMax(&pooled[cur_b * 64 + lane], fmap(mmax));
      cur_b = b;
      mmax = -INFINITY;
    }
    mmax = fmaxf(mmax, x[n * 64 + lane]);
  }
  atomicMax(&pooled[cur_b * 64 + lane], fmap(mmax));
}

// ---------- head: h = BN2(relu(pooled @ W1 + b1)) ----------
__global__ __launch_bounds__(256) void head1_k(
    const unsigned int* __restrict__ pooled, const float* __restrict__ W1,
    const float* __restrict__ b1, const float* __restrict__ g2,
    const float* __restrict__ b2n, const float* __restrict__ m2,
    const float* __restrict__ v2, float* __restrict__ h) {
  __shared__ float p[64];
  const int gidx = blockIdx.x;  // grid = GG
  const int j = threadIdx.x;    // 0..255
  if (j < 64) p[j] = funmap(pooled[gidx * 64 + j]);
  __syncthreads();
  float acc = b1[j];
#pragma unroll 8
  for (int k = 0; k < 64; ++k) acc += p[k] * W1[k * HH + j];
  acc = fmaxf(acc, 0.f);
  acc = (acc - m2[j]) * rsqrtf(v2[j] + EPS_) * g2[j] + b2n[j];
  h[gidx * HH + j] = acc;
}

// ---------- head: out = sigmoid(h @ W2 + b2) ----------
__global__ __launch_bounds__(128) void head2_k(
    const float* __restrict__ h, const float* __restrict__ W2,
    const float* __restrict__ b2, float* __restrict__ out) {
  const int t = threadIdx.x;  // 128 threads
  const int gidx = t >> 1, o = t & 1;
  float acc = b2[o];
#pragma unroll 8
  for (int k = 0; k < HH; ++k) acc += h[gidx * HH + k] * W2[k * OO + o];
  out[gidx * OO + o] = 1.f / (1.f + __expf(-acc));
}

extern "C" void kernel_launch(void* const* d_in, const int* in_sizes, int n_in,
                              void* d_out, int out_size, void* d_ws,
                              size_t ws_size, hipStream_t stream) {
  const float* x    = (const float*)d_in[0];
  const int* ei     = (const int*)d_in[1];
  const float* ea   = (const float*)d_in[2];
  const int* batch  = (const int*)d_in[3];
  const float* Wf   = (const float*)d_in[4];
  const float* bf   = (const float*)d_in[5];
  const float* Ws   = (const float*)d_in[6];
  const float* bs   = (const float*)d_in[7];
  const float* bn_g = (const float*)d_in[8];
  const float* bn_b = (const float*)d_in[9];
  const float* bn_m = (const float*)d_in[10];
  const float* bn_v = (const float*)d_in[11];
  const float* W1   = (const float*)d_in[12];
  const float* b1   = (const float*)d_in[13];
  const float* g2   = (const float*)d_in[14];
  const float* b2n  = (const float*)d_in[15];
  const float* m2   = (const float*)d_in[16];
  const float* v2   = (const float*)d_in[17];
  const float* W2   = (const float*)d_in[18];
  const float* b2   = (const float*)d_in[19];
  float* out = (float*)d_out;

  // workspace layout (~161 MB)
  char* ws = (char*)d_ws;
  float2* Darr   = (float2*)ws;                        // N*64 float2 (25.6 MB)
  unsigned* SarrP = (unsigned*)(Darr + (size_t)N_ * 64);  // N*64 u32 (12.8 MB)
  float* x_cur   = (float*)(SarrP + (size_t)N_ * 64);  // N*F (12.8 MB)
  int* cnt       = (int*)(x_cur + (size_t)N_ * F);     // N (200 KB)
  int* rowptr    = cnt + N_;                           // N+1
  int* cursor    = rowptr + (N_ + 4);                  // N+1 (padded)
  int* csr_src   = cursor + (N_ + 4);                  // E (6.4 MB)
  float* ea_csr  = (float*)(csr_src + E_);             // E*16 f32 (102.4 MB)
  unsigned int* pooled = (unsigned int*)(ea_csr + (size_t)E_ * DEA);  // G*F
  float* h_ws    = (float*)(pooled + GG * F);          // G*H

  const int* srcp = ei;
  const int* dstp = ei + E_;

  constexpr int EDGE_BLOCKS = 2048;
  constexpr int EDGE_WAVES = EDGE_BLOCKS * 4;

  // ---- CSR build (once per call; reused across the 3 layers) ----
  hipMemsetAsync(cnt, 0, N_ * sizeof(int), stream);
  hist_k<<<E_ / 256, 256, 0, stream>>>(dstp, cnt);
  scan_k<<<1, SCAN_T, 0, stream>>>(cnt, rowptr, cursor);
  scatter_k<<<E_ / 256, 256, 0, stream>>>(srcp, dstp, ea, cursor, csr_src,
                                          ea_csr);

  for (int l = 0; l < LL; ++l) {
    const float* xin = (l == 0) ? x : x_cur;
    node_linear_k<<<N_ / 4, 256, 0, stream>>>(
        xin, Wf + (size_t)l * ZIN * F, bf + l * F, Ws + (size_t)l * ZIN * F,
        bs + l * F, Darr, SarrP);
    edge_agg_k<<<EDGE_BLOCKS, 256, 0, stream>>>(
        rowptr, csr_src, ea_csr, Wf + (size_t)l * ZIN * F + 2 * F * F,
        Ws + (size_t)l * ZIN * F + 2 * F * F, Darr, SarrP, xin,
        bn_g + l * F, bn_b + l * F, bn_m + l * F, bn_v + l * F, x_cur,
        EDGE_WAVES);
  }
  hipMemsetAsync(pooled, 0, GG * F * sizeof(unsigned int), stream);
  const int nwaves = (N_ + 31) / 32;
  pool_max_k<<<(nwaves + 3) / 4, 256, 0, stream>>>(x_cur, batch, pooled);
  head1_k<<<GG, 256, 0, stream>>>(pooled, W1, b1, g2, b2n, m2, v2, h_ws);
  head2_k<<<1, 128, 0, stream>>>(h_ws, W2, b2, out);
}

// Round 16
// 1044.174 us; speedup vs baseline: 2.3231x; 1.1661x over previous
//
#include <hip/hip_runtime.h>
#include <math.h>

// Problem constants (match reference)
constexpr int N_  = 50000;
constexpr int E_  = 1600000;
constexpr int F   = 64;
constexpr int DEA = 16;
constexpr int LL  = 3;
constexpr int GG  = 64;
constexpr int HH  = 256;
constexpr int OO  = 2;
constexpr int ZIN = 2 * F + DEA;  // 144
#define EPS_ 1e-5f

typedef float v2f __attribute__((ext_vector_type(2)));

#define LOG2E_ 1.44269504f
#define LN2_ 0.69314718f

// ---------- helpers ----------
__device__ __forceinline__ unsigned int fmap(float f) {
  unsigned int u = __float_as_uint(f);
  return (u & 0x80000000u) ? ~u : (u | 0x80000000u);
}
__device__ __forceinline__ float funmap(unsigned int m) {
  return (m & 0x80000000u) ? __uint_as_float(m ^ 0x80000000u)
                           : __uint_as_float(~m);
}
// round-to-nearest-even f32 -> bf16 (as uint16 in low bits)
__device__ __forceinline__ unsigned f2bf(float f) {
  unsigned u = __float_as_uint(f);
  return (u + 0x7FFFu + ((u >> 16) & 1u)) >> 16;
}

// ---------- per-node linear projections ----------
// 16 nodes/block, 4 per wave -> 4x weight-stream reuse vs 1 node/wave.
// Darr[n][k] = ((x[n] @ Wf[0:64])[k] + bf[k], Ws-version)   [f32 float2]
// SarrP[n][k] = pack_bf16((x[n] @ Wf[64:128])[k], Ws-version) [bf16x2]
__global__ __launch_bounds__(256) void node_linear_k(
    const float* __restrict__ x, const float* __restrict__ Wf,
    const float* __restrict__ bf, const float* __restrict__ Ws,
    const float* __restrict__ bs, float2* __restrict__ Darr,
    unsigned* __restrict__ SarrP) {
  __shared__ float xs[16][64];
  const int wave = threadIdx.x >> 6, lane = threadIdx.x & 63;
  const int nb = blockIdx.x * 16;  // grid = N/16 exact (3125)
#pragma unroll
  for (int j = 0; j < 4; ++j)
    xs[wave * 4 + j][lane] = x[(nb + wave * 4 + j) * 64 + lane];
  // no __syncthreads: each wave reads only rows it wrote (lgkmcnt handles it)
  float df[4] = {0, 0, 0, 0}, sf[4] = {0, 0, 0, 0};
  float ds[4] = {0, 0, 0, 0}, ss[4] = {0, 0, 0, 0};
#pragma unroll 4
  for (int d = 0; d < 64; ++d) {
    const float wf0 = Wf[d * 64 + lane];
    const float wf1 = Wf[(64 + d) * 64 + lane];
    const float ws0 = Ws[d * 64 + lane];
    const float ws1 = Ws[(64 + d) * 64 + lane];
#pragma unroll
    for (int j = 0; j < 4; ++j) {
      const float xv = xs[wave * 4 + j][d];  // LDS broadcast
      df[j] = fmaf(xv, wf0, df[j]);
      sf[j] = fmaf(xv, wf1, sf[j]);
      ds[j] = fmaf(xv, ws0, ds[j]);
      ss[j] = fmaf(xv, ws1, ss[j]);
    }
  }
  const float bfl = bf[lane], bsl = bs[lane];
#pragma unroll
  for (int j = 0; j < 4; ++j) {
    const int n = nb + wave * 4 + j;
    Darr[n * 64 + lane] = make_float2(df[j] + bfl, ds[j] + bsl);
    SarrP[n * 64 + lane] = f2bf(sf[j]) | (f2bf(ss[j]) << 16);
  }
}

// ---------- CSR build: histogram / scan / scatter ----------
__global__ __launch_bounds__(256) void hist_k(const int* __restrict__ dst,
                                              int* __restrict__ cnt) {
  const int e = blockIdx.x * 256 + threadIdx.x;  // grid = E/256 exact
  atomicAdd(&cnt[dst[e]], 1);
}

constexpr int SCAN_T = 1024;
constexpr int CHUNK = 52;  // 13 int4s; 1024*52 = 53248 >= N_+1

__global__ __launch_bounds__(SCAN_T) void scan_k(const int* __restrict__ cnt,
                                                 int* __restrict__ rowptr,
                                                 int* __restrict__ cursor) {
  __shared__ int s[SCAN_T];
  const int t = threadIdx.x;
  int vals[CHUNK];
  const int base = t * CHUNK;
  // vectorized loads (reads past N_ stay inside ws; masked below)
#pragma unroll
  for (int j = 0; j < CHUNK / 4; ++j) {
    const int4 v = *(const int4*)(cnt + base + j * 4);
    vals[j * 4 + 0] = v.x;
    vals[j * 4 + 1] = v.y;
    vals[j * 4 + 2] = v.z;
    vals[j * 4 + 3] = v.w;
  }
  int partial = 0;
#pragma unroll
  for (int j = 0; j < CHUNK; ++j)
    if (base + j < N_) partial += vals[j];
  s[t] = partial;
  __syncthreads();
  for (int off = 1; off < SCAN_T; off <<= 1) {
    int v = (t >= off) ? s[t - off] : 0;
    __syncthreads();
    s[t] += v;
    __syncthreads();
  }
  int run = s[t] - partial;  // exclusive prefix
#pragma unroll
  for (int j = 0; j < CHUNK; ++j) {
    const int idx = base + j;
    if (idx < N_) {
      rowptr[idx] = run;
      cursor[idx] = run;
      run += vals[j];
    } else if (idx == N_) {
      rowptr[idx] = run;  // == E_
    }
  }
}

// scatter edges into CSR order; also pre-gather edge_attr into CSR order
__global__ __launch_bounds__(256) void scatter_k(
    const int* __restrict__ src, const int* __restrict__ dst,
    const float* __restrict__ ea, int* __restrict__ cursor,
    int* __restrict__ csr_src, float* __restrict__ ea_csr) {
  const int e = blockIdx.x * 256 + threadIdx.x;  // grid = E/256 exact
  const int d = dst[e];
  const int pos = atomicAdd(&cursor[d], 1);
  csr_src[pos] = src[e];
  const float4* s4 = (const float4*)(ea + (size_t)e * DEA);
  float4* d4 = (float4*)(ea_csr + (size_t)pos * DEA);
  d4[0] = s4[0];
  d4[1] = s4[1];
  d4[2] = s4[2];
  d4[3] = s4[3];
}

// ---------- per-node edge aggregation + fused BN + residual (+pool) ----------
// One wave per dst node (grid-stride). Weights in VGPRs (asm-pinned, packed
// v2f -> v_pk_fma). Depth-2 prefetch on the SarrP gather to cover HBM-miss
// latency (~900cy; SarrP 12.8MB > 4MiB per-XCD L2 -> ~1/3 gathers miss).
// LAST layer: skip x_cur write, atomicMax straight into pooled[batch[n]].
template <bool LAST>
__global__ __launch_bounds__(256) void edge_agg_k(
    const int* __restrict__ rowptr, const int* __restrict__ csr_src,
    const float* __restrict__ ea_csr, const float* __restrict__ WfE,
    const float* __restrict__ WsE, const float2* __restrict__ Darr,
    const unsigned* __restrict__ SarrP, const float* __restrict__ xin,
    const float* __restrict__ g, const float* __restrict__ b,
    const float* __restrict__ m, const float* __restrict__ v,
    float* __restrict__ xout, const int* __restrict__ batch,
    unsigned* __restrict__ pooled, int nwaves_total) {
  const int lane = threadIdx.x & 63;
  const int wid = blockIdx.x * 4 + (threadIdx.x >> 6);
  v2f w[DEA];
#pragma unroll
  for (int d = 0; d < DEA; ++d) {
    w[d].x = WfE[d * 64 + lane];
    w[d].y = WsE[d * 64 + lane];
  }
  // pin in VGPRs: asm is a def point -> no rematerialization in-loop
#pragma unroll
  for (int d = 0; d < DEA; ++d) asm volatile("" : "+v"(w[d]));
  const float bnm = m[lane];
  const float bnsc = rsqrtf(v[lane] + EPS_) * g[lane];
  const float bnb = b[lane];
  for (int n = wid; n < N_; n += nwaves_total) {
    const int nu = __builtin_amdgcn_readfirstlane(n);
    const int r0 = rowptr[nu], r1 = rowptr[nu + 1];  // s_load
    const float2 dvl = Darr[nu * 64 + lane];
    const v2f dv = {dvl.x, dvl.y};
    float acc = 0.f;
    if (r0 < r1) {
      const int last = r1 - 1;
      unsigned p0 = SarrP[(size_t)csr_src[r0] * 64 + lane];
      const int i1 = (r0 + 1 <= last) ? r0 + 1 : last;
      unsigned p1 = SarrP[(size_t)csr_src[i1] * 64 + lane];
      for (int i = r0; i < r1; ++i) {
        const int iu = __builtin_amdgcn_readfirstlane(i);
        const int i2 = (iu + 2 <= last) ? iu + 2 : last;  // scalar cselect
        const unsigned p2 = SarrP[(size_t)csr_src[i2] * 64 + lane];
        const float* eap = ea_csr + (size_t)iu * DEA;  // scalar s_loads
        v2f gv = dv;
        gv.x += __uint_as_float(p0 << 16);
        gv.y += __uint_as_float(p0 & 0xFFFF0000u);
#pragma unroll
        for (int d = 0; d < DEA; ++d) gv += eap[d] * w[d];  // v_pk_fma_f32
        // fast sigmoid: rcp(1 + 2^(-gf*log2e))
        const float sig = __builtin_amdgcn_rcpf(
            1.f + __builtin_amdgcn_exp2f(gv.x * -LOG2E_));
        // fast stable softplus: max(gs,0) + ln2*log2(1 + 2^(-|gs|*log2e))
        const float t = __builtin_amdgcn_exp2f(-fabsf(gv.y) * LOG2E_);
        const float sp =
            fmaxf(gv.y, 0.f) + LN2_ * __builtin_amdgcn_logf(1.f + t);
        acc = fmaf(sig, sp, acc);
        p0 = p1;
        p1 = p2;
      }
    }
    const float xv = xin[nu * 64 + lane] + (acc - bnm) * bnsc + bnb;
    if constexpr (LAST) {
      const int bidx = batch[nu];  // s_load (uniform)
      atomicMax(&pooled[bidx * 64 + lane], fmap(xv));
    } else {
      xout[nu * 64 + lane] = xv;
    }
  }
}

// ---------- head: h = BN2(relu(pooled @ W1 + b1)) ----------
__global__ __launch_bounds__(256) void head1_k(
    const unsigned int* __restrict__ pooled, const float* __restrict__ W1,
    const float* __restrict__ b1, const float* __restrict__ g2,
    const float* __restrict__ b2n, const float* __restrict__ m2,
    const float* __restrict__ v2, float* __restrict__ h) {
  __shared__ float p[64];
  const int gidx = blockIdx.x;  // grid = GG
  const int j = threadIdx.x;    // 0..255
  if (j < 64) p[j] = funmap(pooled[gidx * 64 + j]);
  __syncthreads();
  float acc = b1[j];
#pragma unroll 8
  for (int k = 0; k < 64; ++k) acc += p[k] * W1[k * HH + j];
  acc = fmaxf(acc, 0.f);
  acc = (acc - m2[j]) * rsqrtf(v2[j] + EPS_) * g2[j] + b2n[j];
  h[gidx * HH + j] = acc;
}

// ---------- head: out = sigmoid(h @ W2 + b2) ----------
__global__ __launch_bounds__(128) void head2_k(
    const float* __restrict__ h, const float* __restrict__ W2,
    const float* __restrict__ b2, float* __restrict__ out) {
  const int t = threadIdx.x;  // 128 threads
  const int gidx = t >> 1, o = t & 1;
  float acc = b2[o];
#pragma unroll 8
  for (int k = 0; k < HH; ++k) acc += h[gidx * HH + k] * W2[k * OO + o];
  out[gidx * OO + o] = 1.f / (1.f + __expf(-acc));
}

extern "C" void kernel_launch(void* const* d_in, const int* in_sizes, int n_in,
                              void* d_out, int out_size, void* d_ws,
                              size_t ws_size, hipStream_t stream) {
  const float* x    = (const float*)d_in[0];
  const int* ei     = (const int*)d_in[1];
  const float* ea   = (const float*)d_in[2];
  const int* batch  = (const int*)d_in[3];
  const float* Wf   = (const float*)d_in[4];
  const float* bf   = (const float*)d_in[5];
  const float* Ws   = (const float*)d_in[6];
  const float* bs   = (const float*)d_in[7];
  const float* bn_g = (const float*)d_in[8];
  const float* bn_b = (const float*)d_in[9];
  const float* bn_m = (const float*)d_in[10];
  const float* bn_v = (const float*)d_in[11];
  const float* W1   = (const float*)d_in[12];
  const float* b1   = (const float*)d_in[13];
  const float* g2   = (const float*)d_in[14];
  const float* b2n  = (const float*)d_in[15];
  const float* m2   = (const float*)d_in[16];
  const float* v2   = (const float*)d_in[17];
  const float* W2   = (const float*)d_in[18];
  const float* b2   = (const float*)d_in[19];
  float* out = (float*)d_out;

  // workspace layout (~161 MB)
  char* ws = (char*)d_ws;
  float2* Darr   = (float2*)ws;                        // N*64 float2 (25.6 MB)
  unsigned* SarrP = (unsigned*)(Darr + (size_t)N_ * 64);  // N*64 u32 (12.8 MB)
  float* x_cur   = (float*)(SarrP + (size_t)N_ * 64);  // N*F (12.8 MB)
  int* cnt       = (int*)(x_cur + (size_t)N_ * F);     // N (200 KB)
  int* rowptr    = cnt + N_;                           // N+1
  int* cursor    = rowptr + (N_ + 4);                  // N+1 (padded)
  int* csr_src   = cursor + (N_ + 4);                  // E (6.4 MB)
  float* ea_csr  = (float*)(csr_src + E_);             // E*16 f32 (102.4 MB)
  unsigned int* pooled = (unsigned int*)(ea_csr + (size_t)E_ * DEA);  // G*F
  float* h_ws    = (float*)(pooled + GG * F);          // G*H

  const int* srcp = ei;
  const int* dstp = ei + E_;

  constexpr int EDGE_BLOCKS = 2048;
  constexpr int EDGE_WAVES = EDGE_BLOCKS * 4;

  // ---- CSR build (once per call; reused across the 3 layers) ----
  hipMemsetAsync(cnt, 0, N_ * sizeof(int), stream);
  hipMemsetAsync(pooled, 0, GG * F * sizeof(unsigned int), stream);
  hist_k<<<E_ / 256, 256, 0, stream>>>(dstp, cnt);
  scan_k<<<1, SCAN_T, 0, stream>>>(cnt, rowptr, cursor);
  scatter_k<<<E_ / 256, 256, 0, stream>>>(srcp, dstp, ea, cursor, csr_src,
                                          ea_csr);

  for (int l = 0; l < LL; ++l) {
    const float* xin = (l == 0) ? x : x_cur;
    node_linear_k<<<N_ / 16, 256, 0, stream>>>(
        xin, Wf + (size_t)l * ZIN * F, bf + l * F, Ws + (size_t)l * ZIN * F,
        bs + l * F, Darr, SarrP);
    const float* WfEl = Wf + (size_t)l * ZIN * F + 2 * F * F;
    const float* WsEl = Ws + (size_t)l * ZIN * F + 2 * F * F;
    if (l < LL - 1) {
      edge_agg_k<false><<<EDGE_BLOCKS, 256, 0, stream>>>(
          rowptr, csr_src, ea_csr, WfEl, WsEl, Darr, SarrP, xin,
          bn_g + l * F, bn_b + l * F, bn_m + l * F, bn_v + l * F, x_cur,
          batch, pooled, EDGE_WAVES);
    } else {
      edge_agg_k<true><<<EDGE_BLOCKS, 256, 0, stream>>>(
          rowptr, csr_src, ea_csr, WfEl, WsEl, Darr, SarrP, xin,
          bn_g + l * F, bn_b + l * F, bn_m + l * F, bn_v + l * F, x_cur,
          batch, pooled, EDGE_WAVES);
    }
  }
  head1_k<<<GG, 256, 0, stream>>>(pooled, W1, b1, g2, b2n, m2, v2, h_ws);
  head2_k<<<1, 128, 0, stream>>>(h_ws, W2, b2, out);
}